// Round 17
// baseline (519.165 us; speedup 1.0000x reference)
//
#include <hip/hip_runtime.h>
#include <math.h>

#define SDIM 512
#define BDIM 64
#define HDIM 512
#define TDIM 32
#define MTOT (SDIM * BDIM)

typedef __attribute__((ext_vector_type(8))) short bf16x8;
typedef __attribute__((ext_vector_type(4))) float f32x4;

// static device scratch
__device__ unsigned short g_w1hT[HDIM * HDIM];  // W1^T hi [n][k]
__device__ unsigned short g_w1lT[HDIM * HDIM];  // W1^T lo [n][k]
__device__ unsigned short g_w2hT[TDIM * HDIM];  // W2^T hi [t][k]
__device__ unsigned short g_w2lT[TDIM * HDIM];  // W2^T lo [t][k]
__device__ float g_em[(size_t)MTOT * TDIM];     // 4 MB emissions, b-major
__device__ unsigned int g_flag[SDIM];           // per-timestep ready flags

__device__ __forceinline__ unsigned short f2bf(float x) {
  union { float f; unsigned int u; } v; v.f = x;
  unsigned int r = v.u + 0x7FFFu + ((v.u >> 16) & 1u);  // RNE
  return (unsigned short)(r >> 16);
}
__device__ __forceinline__ float bf2f(unsigned short h) {
  union { float f; unsigned int u; } v; v.u = ((unsigned int)h) << 16; return v.f;
}
__device__ __forceinline__ float fmax3(float a, float b, float c) {
  return fmaxf(fmaxf(a, b), c);  // fuses to v_max3_f32
}
__device__ __forceinline__ int imin3(int a, int b, int c) {
  int m = a < b ? a : b; return m < c ? m : c;  // fuses to v_min3_i32
}
__device__ __forceinline__ void wait_flag(int s) {
  while (__hip_atomic_load(&g_flag[s], __ATOMIC_ACQUIRE,
                           __HIP_MEMORY_SCOPE_AGENT) == 0u) {
    __builtin_amdgcn_s_sleep(2);
  }
}

// ---------------- init flags ----------------
__global__ void init_flags() {
  int i = blockIdx.x * blockDim.x + threadIdx.x;
  if (i < SDIM) g_flag[i] = 0u;
}

// ---------------- W1/W2 split + transpose ----------------
__global__ void split_kernel(const float* __restrict__ W1, const float* __restrict__ W2) {
  const int n = blockIdx.x;
  const int k0 = threadIdx.x * 4;
  if (n < HDIM) {
    ushort4 h, l; float x;
    x = W1[(size_t)(k0 + 0) * HDIM + n]; h.x = f2bf(x); l.x = f2bf(x - bf2f(h.x));
    x = W1[(size_t)(k0 + 1) * HDIM + n]; h.y = f2bf(x); l.y = f2bf(x - bf2f(h.y));
    x = W1[(size_t)(k0 + 2) * HDIM + n]; h.z = f2bf(x); l.z = f2bf(x - bf2f(h.z));
    x = W1[(size_t)(k0 + 3) * HDIM + n]; h.w = f2bf(x); l.w = f2bf(x - bf2f(h.w));
    *(ushort4*)&g_w1hT[(size_t)n * HDIM + k0] = h;
    *(ushort4*)&g_w1lT[(size_t)n * HDIM + k0] = l;
  } else {
    const int t = n - HDIM;
    ushort4 h, l; float x;
    x = W2[(size_t)(k0 + 0) * TDIM + t]; h.x = f2bf(x); l.x = f2bf(x - bf2f(h.x));
    x = W2[(size_t)(k0 + 1) * TDIM + t]; h.y = f2bf(x); l.y = f2bf(x - bf2f(h.y));
    x = W2[(size_t)(k0 + 2) * TDIM + t]; h.z = f2bf(x); l.z = f2bf(x - bf2f(h.z));
    x = W2[(size_t)(k0 + 3) * TDIM + t]; h.w = f2bf(x); l.w = f2bf(x - bf2f(h.w));
    *(ushort4*)&g_w2hT[(size_t)t * HDIM + k0] = h;
    *(ushort4*)&g_w2lT[(size_t)t * HDIM + k0] = l;
  }
}

// ---------------- Fused producer/consumer kernel ----------------
// blocks [0,512): emis role (timestep s = blockIdx); blocks [512,528): viterbi
// role, 4 chains per block (1 per wave).
__global__ __launch_bounds__(256) void fused_kernel(
    const float* __restrict__ hidden, const float* __restrict__ b1,
    const float* __restrict__ b2, const int* __restrict__ lens,
    const float* __restrict__ trans, float* __restrict__ out)
{
  __shared__ __attribute__((aligned(16))) unsigned char raw[66560];

  if (blockIdx.x < SDIM) {
    // ================= emis role (r15 body, proven absmax 0) =================
    unsigned short (*lAh)[40] = (unsigned short(*)[40])(raw + 0);
    unsigned short (*lAl)[40] = (unsigned short(*)[40])(raw + 5120);
    unsigned short (*lBh)[40] = (unsigned short(*)[40])(raw + 10240);
    unsigned short (*lBl)[40] = (unsigned short(*)[40])(raw + 20480);
    unsigned short (*H1h)[136] = (unsigned short(*)[136])(raw + 30720);
    unsigned short (*H1l)[136] = (unsigned short(*)[136])(raw + 48128);

    const int tid = threadIdx.x;
    const int s = blockIdx.x;
    const int row0 = s * 64;
    const int wave = tid >> 6;
    const int lane = tid & 63;
    const int l15 = lane & 15;
    const int l4 = lane >> 4;
    const int wr1 = (wave >> 1) * 32;
    const int wc1 = (wave & 1) * 64;

    f32x4 acc_em[2];
    acc_em[0] = (f32x4)(0.f);
    acc_em[1] = (f32x4)(0.f);

    for (int jcb = 0; jcb < 4; ++jcb) {
      const int jc = jcb * 128;

      f32x4 acc1[2][4];
#pragma unroll
      for (int i = 0; i < 2; ++i)
#pragma unroll
        for (int j = 0; j < 4; ++j) acc1[i][j] = (f32x4)(0.f);

      for (int k0 = 0; k0 < HDIM; k0 += 32) {
#pragma unroll
        for (int i = 0; i < 2; ++i) {
          int f4 = tid + 256 * i;
          int r = f4 >> 3, q = f4 & 7;
          float4 v = *(const float4*)&hidden[(size_t)(row0 + r) * HDIM + k0 + 4 * q];
          ushort4 h, l;
          h.x = f2bf(v.x); l.x = f2bf(v.x - bf2f(h.x));
          h.y = f2bf(v.y); l.y = f2bf(v.y - bf2f(h.y));
          h.z = f2bf(v.z); l.z = f2bf(v.z - bf2f(h.z));
          h.w = f2bf(v.w); l.w = f2bf(v.w - bf2f(h.w));
          *(ushort4*)&lAh[r][4 * q] = h;
          *(ushort4*)&lAl[r][4 * q] = l;
        }
#pragma unroll
        for (int i = 0; i < 2; ++i) {
          int f8 = tid + 256 * i;
          int nl = f8 >> 2, kq8 = f8 & 3;
          *(uint4*)&lBh[nl][8 * kq8] =
              *(const uint4*)&g_w1hT[(size_t)(jc + nl) * HDIM + k0 + 8 * kq8];
          *(uint4*)&lBl[nl][8 * kq8] =
              *(const uint4*)&g_w1lT[(size_t)(jc + nl) * HDIM + k0 + 8 * kq8];
        }
        __syncthreads();

        bf16x8 aH[2], aL[2];
#pragma unroll
        for (int i = 0; i < 2; ++i) {
          aH[i] = *(const bf16x8*)&lAh[wr1 + 16 * i + l15][8 * l4];
          aL[i] = *(const bf16x8*)&lAl[wr1 + 16 * i + l15][8 * l4];
        }
#pragma unroll
        for (int j = 0; j < 4; ++j) {
          bf16x8 bH = *(const bf16x8*)&lBh[wc1 + 16 * j + l15][8 * l4];
          bf16x8 bL = *(const bf16x8*)&lBl[wc1 + 16 * j + l15][8 * l4];
#pragma unroll
          for (int i = 0; i < 2; ++i) {
            acc1[i][j] = __builtin_amdgcn_mfma_f32_16x16x32_bf16(aH[i], bH, acc1[i][j], 0, 0, 0);
            acc1[i][j] = __builtin_amdgcn_mfma_f32_16x16x32_bf16(aH[i], bL, acc1[i][j], 0, 0, 0);
            acc1[i][j] = __builtin_amdgcn_mfma_f32_16x16x32_bf16(aL[i], bH, acc1[i][j], 0, 0, 0);
          }
        }
        __syncthreads();
      }

#pragma unroll
      for (int j = 0; j < 4; ++j) {
        const int col = wc1 + 16 * j + l15;
        const float bv = b1[jc + col];
#pragma unroll
        for (int i = 0; i < 2; ++i) {
#pragma unroll
          for (int r = 0; r < 4; ++r) {
            int lrow = wr1 + 16 * i + 4 * l4 + r;
            float h = 1.f / (1.f + __expf(-(acc1[i][j][r] + bv)));
            unsigned short hh = f2bf(h);
            unsigned short hl = f2bf(h - bf2f(hh));
            H1h[lrow][col] = hh;
            H1l[lrow][col] = hl;
          }
        }
      }
      __syncthreads();

#pragma unroll
      for (int ks = 0; ks < 4; ++ks) {
        bf16x8 aH2 = *(const bf16x8*)&H1h[16 * wave + l15][32 * ks + 8 * l4];
        bf16x8 aL2 = *(const bf16x8*)&H1l[16 * wave + l15][32 * ks + 8 * l4];
#pragma unroll
        for (int j2 = 0; j2 < 2; ++j2) {
          const size_t wo = (size_t)(16 * j2 + l15) * HDIM + jc + 32 * ks + 8 * l4;
          bf16x8 bH2 = *(const bf16x8*)&g_w2hT[wo];
          bf16x8 bL2 = *(const bf16x8*)&g_w2lT[wo];
          acc_em[j2] = __builtin_amdgcn_mfma_f32_16x16x32_bf16(aH2, bH2, acc_em[j2], 0, 0, 0);
          acc_em[j2] = __builtin_amdgcn_mfma_f32_16x16x32_bf16(aH2, bL2, acc_em[j2], 0, 0, 0);
          acc_em[j2] = __builtin_amdgcn_mfma_f32_16x16x32_bf16(aL2, bH2, acc_em[j2], 0, 0, 0);
        }
      }
      __syncthreads();
    }

#pragma unroll
    for (int j2 = 0; j2 < 2; ++j2) {
      const int t = 16 * j2 + l15;
      const float bv = b2[t];
#pragma unroll
      for (int r = 0; r < 4; ++r) {
        int bb = 16 * wave + 4 * l4 + r;
        g_em[((size_t)bb * SDIM + s) * TDIM + t] = acc_em[j2][r] + bv;
      }
    }

    // publish: all block stores drained (syncthreads emits vmcnt(0)), then
    // device-scope release of this timestep's flag.
    __syncthreads();
    if (tid == 0) {
      __threadfence();
      __hip_atomic_store(&g_flag[s], 1u, __ATOMIC_RELEASE, __HIP_MEMORY_SCOPE_AGENT);
    }
  } else {
    // ================= viterbi role: v7 (r13, proven 125 us), 1 chain/wave ====
    unsigned int (*bpsw)[TDIM] =
        (unsigned int(*)[TDIM])(raw + (size_t)(threadIdx.x >> 6) * (SDIM / 4) * TDIM * 4);
    float* fvw = (float*)(raw + 65536) + (threadIdx.x >> 6) * 64;

    const int tid = threadIdx.x;
    const int wave = tid >> 6;
    const int lane = tid & 63;
    const int c = lane & 31;
    const int h = lane >> 5;
    const int p0 = 16 * h;
    const int b = (blockIdx.x - SDIM) * 4 + wave;

    float tr[16];
#pragma unroll
    for (int j = 0; j < 16; j += 4) {
      float4 t4 = *(const float4*)&trans[c * TDIM + p0 + j];
      tr[j] = t4.x; tr[j + 1] = t4.y; tr[j + 2] = t4.z; tr[j + 3] = t4.w;
    }

    int len;
    { const int* p32 = lens;
      len = (p32[1] == 0) ? (int)((const long long*)lens)[b] : p32[b]; }

    const float* emc = g_em + (size_t)b * SDIM * TDIM + c;

    // gate t = 0..12 before initial loads
    for (int j = 0; j <= 12; ++j) wait_flag(j);

    float fvown = emc[0];  // t = 0 (dup across halves)
    fvw[lane] = fvown;

    float ebuf[12];
#pragma unroll
    for (int j = 0; j < 12; ++j) ebuf[j] = emc[(size_t)(1 + j) * TDIM];

    unsigned int bpk = 0u;

#define VSTEP(T, PH, EV)                                                       \
  {                                                                            \
    float4 q0 = *(const float4*)&fvw[p0];                                      \
    float4 q1 = *(const float4*)&fvw[p0 + 4];                                  \
    float4 q2 = *(const float4*)&fvw[p0 + 8];                                  \
    float4 q3 = *(const float4*)&fvw[p0 + 12];                                 \
    float sv[16];                                                              \
    sv[0] = q0.x + tr[0];  sv[1] = q0.y + tr[1];                               \
    sv[2] = q0.z + tr[2];  sv[3] = q0.w + tr[3];                               \
    sv[4] = q1.x + tr[4];  sv[5] = q1.y + tr[5];                               \
    sv[6] = q1.z + tr[6];  sv[7] = q1.w + tr[7];                               \
    sv[8] = q2.x + tr[8];  sv[9] = q2.y + tr[9];                               \
    sv[10] = q2.z + tr[10]; sv[11] = q2.w + tr[11];                            \
    sv[12] = q3.x + tr[12]; sv[13] = q3.y + tr[13];                            \
    sv[14] = q3.z + tr[14]; sv[15] = q3.w + tr[15];                            \
    float l0 = fmax3(sv[0], sv[1], sv[2]);                                     \
    float l1 = fmax3(sv[3], sv[4], sv[5]);                                     \
    float l2 = fmax3(sv[6], sv[7], sv[8]);                                     \
    float l3 = fmax3(sv[9], sv[10], sv[11]);                                   \
    float l4 = fmax3(sv[12], sv[13], sv[14]);                                  \
    float mh = fmaxf(fmax3(l0, l1, l2), fmax3(l3, l4, sv[15]));                \
    float mo = __shfl_xor(mh, 32, 64);                                         \
    float m0 = fmaxf(mh, mo);                                                  \
    const bool act = (T) < len;                                                \
    fvown = act ? (m0 + (EV)) : fvown;                                         \
    fvw[lane] = fvown;                                                         \
    int i_[16];                                                                \
    _Pragma("unroll")                                                          \
    for (int j = 0; j < 16; ++j) i_[j] = (sv[j] == m0) ? j : 63;               \
    int u0 = imin3(i_[0], i_[1], i_[2]);                                       \
    int u1 = imin3(i_[3], i_[4], i_[5]);                                       \
    int u2 = imin3(i_[6], i_[7], i_[8]);                                       \
    int u3 = imin3(i_[9], i_[10], i_[11]);                                     \
    int u4 = imin3(i_[12], i_[13], i_[14]);                                    \
    int jm = imin3(imin3(u0, u1, u2), imin3(u3, u4, i_[15]), 63);              \
    int gi = (jm == 63) ? 255 : (p0 + jm);                                     \
    int go = __shfl_xor(gi, 32, 64);                                           \
    int im = gi < go ? gi : go;                                                \
    int bp = act ? im : c;                                                     \
    bpk |= (unsigned)bp << (8 * (PH));                                         \
    if ((PH) == 3) { bpsw[(T) >> 2][c] = bpk; bpk = 0u; }                      \
  }

#define LOADQ(BASE, T0)                                                        \
  {                                                                            \
    _Pragma("unroll")                                                          \
    for (int j = 0; j < 4; ++j) {                                              \
      int lt = (T0) + j; lt = lt > (SDIM - 1) ? (SDIM - 1) : lt;               \
      wait_flag(lt);                                                           \
      ebuf[(BASE) + j] = emc[(size_t)lt * TDIM];                               \
    }                                                                          \
  }

    {
      int tq = 1;
      for (; tq <= SDIM - 19; tq += 12) {  // t = 1..504
        VSTEP(tq + 0, 1, ebuf[0]) VSTEP(tq + 1, 2, ebuf[1])
        VSTEP(tq + 2, 3, ebuf[2]) VSTEP(tq + 3, 0, ebuf[3])
        LOADQ(0, tq + 12)
        VSTEP(tq + 4, 1, ebuf[4]) VSTEP(tq + 5, 2, ebuf[5])
        VSTEP(tq + 6, 3, ebuf[6]) VSTEP(tq + 7, 0, ebuf[7])
        LOADQ(4, tq + 16)
        VSTEP(tq + 8, 1, ebuf[8]) VSTEP(tq + 9, 2, ebuf[9])
        VSTEP(tq + 10, 3, ebuf[10]) VSTEP(tq + 11, 0, ebuf[11])
        LOADQ(8, tq + 20)
      }
      // tail: t = 505..511
      VSTEP(505, 1, ebuf[0]) VSTEP(506, 2, ebuf[1]) VSTEP(507, 3, ebuf[2])
      VSTEP(508, 0, ebuf[3]) VSTEP(509, 1, ebuf[4]) VSTEP(510, 2, ebuf[5])
      VSTEP(511, 3, ebuf[6])
    }
#undef VSTEP
#undef LOADQ

    // final argmax over tags (values dup across halves; lowest index wins)
    float bs = fvown;
    int bi = c;
#pragma unroll
    for (int off = 16; off > 0; off >>= 1) {
      float os = __shfl_down(bs, off, 32);
      int oi = __shfl_down(bi, off, 32);
      if (os > bs || (os == bs && oi < bi)) { bs = os; bi = oi; }
    }
    bs = __shfl(bs, 0, 32);
    int tag = __shfl(bi, 0, 32);  // uniform within wave

    out[(size_t)SDIM * BDIM + b] = bs;
    out[(size_t)(SDIM - 1) * BDIM + b] = (float)tag;

    // scalar backtrack via readlane over packed bps words
    unsigned bw_next = bpsw[SDIM / 4 - 1][c];
    for (int w = SDIM / 4 - 1; w >= 0; --w) {
      unsigned bw = bw_next;
      if (w > 0) bw_next = bpsw[w - 1][c];
#pragma unroll
      for (int j = 3; j >= 0; --j) {
        int t = 4 * w + j;
        if (t < 1) continue;
        unsigned word = (unsigned)__builtin_amdgcn_readlane((int)bw, tag);
        tag = (int)((word >> (8 * j)) & 255u);
        out[(size_t)(t - 1) * BDIM + b] = (float)tag;
      }
    }
  }
}

// ---------------- host ----------------
static int find_by_size(const int* in_sizes, int n_in, int sz, int fb) {
  for (int i = 0; i < n_in; ++i) if (in_sizes[i] == sz) return i;
  return fb;
}

extern "C" void kernel_launch(void* const* d_in, const int* in_sizes, int n_in,
                              void* d_out, int out_size, void* d_ws, size_t ws_size,
                              hipStream_t stream) {
  const int i_hidden = find_by_size(in_sizes, n_in, SDIM * BDIM * HDIM, 0);
  const int i_lens   = find_by_size(in_sizes, n_in, BDIM, 1);
  const int i_W1     = find_by_size(in_sizes, n_in, HDIM * HDIM, 3);
  const int i_b1     = find_by_size(in_sizes, n_in, HDIM, 4);
  const int i_W2     = find_by_size(in_sizes, n_in, HDIM * TDIM, 5);
  const int i_b2     = find_by_size(in_sizes, n_in, TDIM, 6);
  const int i_tr     = find_by_size(in_sizes, n_in, TDIM * TDIM, 7);

  const float* hidden = (const float*)d_in[i_hidden];
  const int*   lens   = (const int*)d_in[i_lens];
  const float* W1     = (const float*)d_in[i_W1];
  const float* b1     = (const float*)d_in[i_b1];
  const float* W2     = (const float*)d_in[i_W2];
  const float* b2     = (const float*)d_in[i_b2];
  const float* trans  = (const float*)d_in[i_tr];
  float* out = (float*)d_out;

  init_flags<<<2, 256, 0, stream>>>();
  split_kernel<<<HDIM + TDIM, 128, 0, stream>>>(W1, W2);
  fused_kernel<<<SDIM + BDIM / 4, 256, 0, stream>>>(hidden, b1, b2, lens, trans, out);
}

// Round 19
// 228.630 us; speedup vs baseline: 2.2708x; 2.2708x over previous
//
#include <hip/hip_runtime.h>
#include <math.h>

#define SDIM 512
#define BDIM 64
#define HDIM 512
#define TDIM 32
#define MTOT (SDIM * BDIM)

typedef __attribute__((ext_vector_type(8))) short bf16x8;
typedef __attribute__((ext_vector_type(4))) float f32x4;
typedef __attribute__((ext_vector_type(2))) int int2v;

// static device scratch
__device__ unsigned short g_w1hT[HDIM * HDIM];  // W1^T hi [n][k]
__device__ unsigned short g_w1lT[HDIM * HDIM];  // W1^T lo [n][k]
__device__ unsigned short g_w2hT[TDIM * HDIM];  // W2^T hi [t][k]
__device__ unsigned short g_w2lT[TDIM * HDIM];  // W2^T lo [t][k]
__device__ float g_em[(size_t)MTOT * TDIM];     // 4 MB emissions, b-major

__device__ __forceinline__ unsigned short f2bf(float x) {
  union { float f; unsigned int u; } v; v.f = x;
  unsigned int r = v.u + 0x7FFFu + ((v.u >> 16) & 1u);  // RNE
  return (unsigned short)(r >> 16);
}
__device__ __forceinline__ float bf2f(unsigned short h) {
  union { float f; unsigned int u; } v; v.u = ((unsigned int)h) << 16; return v.f;
}
__device__ __forceinline__ float fmax3(float a, float b, float c) {
  return fmaxf(fmaxf(a, b), c);  // fuses to v_max3_f32
}
__device__ __forceinline__ int imin3(int a, int b, int c) {
  int m = a < b ? a : b; return m < c ? m : c;  // fuses to v_min3_i32
}

// lane[i] <-> lane[i^32] exchange on the VALU pipe (permlane32_swap).
// Semantics with A=B=x: p[0][l<32]=x[l], p[0][l>=32]=x[l-32],
//                       p[1][l<32]=x[l+32], p[1][l>=32]=x[l].
// Cross-half value: low half (h=0) -> p[1]; high half (h=1) -> p[0].
__device__ __forceinline__ int xor32_i(int x, int h) {
#if __has_builtin(__builtin_amdgcn_permlane32_swap)
  int2v p = __builtin_amdgcn_permlane32_swap(x, x, false, false);
  return h ? p[0] : p[1];
#else
  return __shfl_xor(x, 32, 64);
#endif
}
__device__ __forceinline__ float xor32_f(float x, int h) {
  return __int_as_float(xor32_i(__float_as_int(x), h));
}

// ---------------- W1/W2 split + transpose ----------------
__global__ void split_kernel(const float* __restrict__ W1, const float* __restrict__ W2) {
  const int n = blockIdx.x;
  const int k0 = threadIdx.x * 4;
  if (n < HDIM) {
    ushort4 h, l; float x;
    x = W1[(size_t)(k0 + 0) * HDIM + n]; h.x = f2bf(x); l.x = f2bf(x - bf2f(h.x));
    x = W1[(size_t)(k0 + 1) * HDIM + n]; h.y = f2bf(x); l.y = f2bf(x - bf2f(h.y));
    x = W1[(size_t)(k0 + 2) * HDIM + n]; h.z = f2bf(x); l.z = f2bf(x - bf2f(h.z));
    x = W1[(size_t)(k0 + 3) * HDIM + n]; h.w = f2bf(x); l.w = f2bf(x - bf2f(h.w));
    *(ushort4*)&g_w1hT[(size_t)n * HDIM + k0] = h;
    *(ushort4*)&g_w1lT[(size_t)n * HDIM + k0] = l;
  } else {
    const int t = n - HDIM;
    ushort4 h, l; float x;
    x = W2[(size_t)(k0 + 0) * TDIM + t]; h.x = f2bf(x); l.x = f2bf(x - bf2f(h.x));
    x = W2[(size_t)(k0 + 1) * TDIM + t]; h.y = f2bf(x); l.y = f2bf(x - bf2f(h.y));
    x = W2[(size_t)(k0 + 2) * TDIM + t]; h.z = f2bf(x); l.z = f2bf(x - bf2f(h.z));
    x = W2[(size_t)(k0 + 3) * TDIM + t]; h.w = f2bf(x); l.w = f2bf(x - bf2f(h.w));
    *(ushort4*)&g_w2hT[(size_t)t * HDIM + k0] = h;
    *(ushort4*)&g_w2lT[(size_t)t * HDIM + k0] = l;
  }
}

// ---------------- Fused emissions (r15 version, proven ~108 us, absmax 0) ----------------
__global__ __launch_bounds__(256) void emis_kernel(
    const float* __restrict__ hidden, const float* __restrict__ b1,
    const float* __restrict__ b2)
{
  __shared__ unsigned short lAh[64][40];
  __shared__ unsigned short lAl[64][40];
  __shared__ unsigned short lBh[128][40];
  __shared__ unsigned short lBl[128][40];
  __shared__ unsigned short H1h[64][136];
  __shared__ unsigned short H1l[64][136];

  const int tid = threadIdx.x;
  const int s = blockIdx.x;
  const int row0 = s * 64;
  const int wave = tid >> 6;
  const int lane = tid & 63;
  const int l15 = lane & 15;
  const int l4 = lane >> 4;
  const int wr1 = (wave >> 1) * 32;
  const int wc1 = (wave & 1) * 64;

  f32x4 acc_em[2];
  acc_em[0] = (f32x4)(0.f);
  acc_em[1] = (f32x4)(0.f);

  for (int jcb = 0; jcb < 4; ++jcb) {
    const int jc = jcb * 128;

    f32x4 acc1[2][4];
#pragma unroll
    for (int i = 0; i < 2; ++i)
#pragma unroll
      for (int j = 0; j < 4; ++j) acc1[i][j] = (f32x4)(0.f);

    for (int k0 = 0; k0 < HDIM; k0 += 32) {
#pragma unroll
      for (int i = 0; i < 2; ++i) {
        int f4 = tid + 256 * i;
        int r = f4 >> 3, q = f4 & 7;
        float4 v = *(const float4*)&hidden[(size_t)(row0 + r) * HDIM + k0 + 4 * q];
        ushort4 h, l;
        h.x = f2bf(v.x); l.x = f2bf(v.x - bf2f(h.x));
        h.y = f2bf(v.y); l.y = f2bf(v.y - bf2f(h.y));
        h.z = f2bf(v.z); l.z = f2bf(v.z - bf2f(h.z));
        h.w = f2bf(v.w); l.w = f2bf(v.w - bf2f(h.w));
        *(ushort4*)&lAh[r][4 * q] = h;
        *(ushort4*)&lAl[r][4 * q] = l;
      }
#pragma unroll
      for (int i = 0; i < 2; ++i) {
        int f8 = tid + 256 * i;
        int nl = f8 >> 2, kq8 = f8 & 3;
        *(uint4*)&lBh[nl][8 * kq8] =
            *(const uint4*)&g_w1hT[(size_t)(jc + nl) * HDIM + k0 + 8 * kq8];
        *(uint4*)&lBl[nl][8 * kq8] =
            *(const uint4*)&g_w1lT[(size_t)(jc + nl) * HDIM + k0 + 8 * kq8];
      }
      __syncthreads();

      bf16x8 aH[2], aL[2];
#pragma unroll
      for (int i = 0; i < 2; ++i) {
        aH[i] = *(const bf16x8*)&lAh[wr1 + 16 * i + l15][8 * l4];
        aL[i] = *(const bf16x8*)&lAl[wr1 + 16 * i + l15][8 * l4];
      }
#pragma unroll
      for (int j = 0; j < 4; ++j) {
        bf16x8 bH = *(const bf16x8*)&lBh[wc1 + 16 * j + l15][8 * l4];
        bf16x8 bL = *(const bf16x8*)&lBl[wc1 + 16 * j + l15][8 * l4];
#pragma unroll
        for (int i = 0; i < 2; ++i) {
          acc1[i][j] = __builtin_amdgcn_mfma_f32_16x16x32_bf16(aH[i], bH, acc1[i][j], 0, 0, 0);
          acc1[i][j] = __builtin_amdgcn_mfma_f32_16x16x32_bf16(aH[i], bL, acc1[i][j], 0, 0, 0);
          acc1[i][j] = __builtin_amdgcn_mfma_f32_16x16x32_bf16(aL[i], bH, acc1[i][j], 0, 0, 0);
        }
      }
      __syncthreads();
    }

#pragma unroll
    for (int j = 0; j < 4; ++j) {
      const int col = wc1 + 16 * j + l15;
      const float bv = b1[jc + col];
#pragma unroll
      for (int i = 0; i < 2; ++i) {
#pragma unroll
        for (int r = 0; r < 4; ++r) {
          int lrow = wr1 + 16 * i + 4 * l4 + r;
          float h = 1.f / (1.f + __expf(-(acc1[i][j][r] + bv)));
          unsigned short hh = f2bf(h);
          unsigned short hl = f2bf(h - bf2f(hh));
          H1h[lrow][col] = hh;
          H1l[lrow][col] = hl;
        }
      }
    }
    __syncthreads();

#pragma unroll
    for (int ks = 0; ks < 4; ++ks) {
      bf16x8 aH2 = *(const bf16x8*)&H1h[16 * wave + l15][32 * ks + 8 * l4];
      bf16x8 aL2 = *(const bf16x8*)&H1l[16 * wave + l15][32 * ks + 8 * l4];
#pragma unroll
      for (int j2 = 0; j2 < 2; ++j2) {
        const size_t wo = (size_t)(16 * j2 + l15) * HDIM + jc + 32 * ks + 8 * l4;
        bf16x8 bH2 = *(const bf16x8*)&g_w2hT[wo];
        bf16x8 bL2 = *(const bf16x8*)&g_w2lT[wo];
        acc_em[j2] = __builtin_amdgcn_mfma_f32_16x16x32_bf16(aH2, bH2, acc_em[j2], 0, 0, 0);
        acc_em[j2] = __builtin_amdgcn_mfma_f32_16x16x32_bf16(aH2, bL2, acc_em[j2], 0, 0, 0);
        acc_em[j2] = __builtin_amdgcn_mfma_f32_16x16x32_bf16(aL2, bH2, acc_em[j2], 0, 0, 0);
      }
    }
    __syncthreads();
  }

#pragma unroll
  for (int j2 = 0; j2 < 2; ++j2) {
    const int t = 16 * j2 + l15;
    const float bv = b2[t];
#pragma unroll
    for (int r = 0; r < 4; ++r) {
      int b = 16 * wave + 4 * l4 + r;
      g_em[((size_t)b * SDIM + s) * TDIM + t] = acc_em[j2][r] + bv;
    }
  }
}

// ---------------- Viterbi v11b: v7 with corrected permlane32_swap merges ----------------
__global__ __launch_bounds__(64) void viterbi_kernel(
    const int* __restrict__ lens, const float* __restrict__ trans,
    float* __restrict__ out)
{
  __shared__ float fvL[64];                       // [0..31] canonical, [32..63] dup
  __shared__ unsigned int bps32[SDIM / 4][TDIM];  // 16 KB
  const int b = blockIdx.x;
  const int lane = threadIdx.x;
  const int c = lane & 31;
  const int h = lane >> 5;
  const int p0 = 16 * h;  // this half's prev range [p0, p0+16)

  // tr[j] = trans[c][p0 + j]
  float tr[16];
#pragma unroll
  for (int j = 0; j < 16; j += 4) {
    float4 t4 = *(const float4*)&trans[c * TDIM + p0 + j];
    tr[j] = t4.x; tr[j + 1] = t4.y; tr[j + 2] = t4.z; tr[j + 3] = t4.w;
  }

  int len;
  { const int* p32 = lens;
    len = (p32[1] == 0) ? (int)((const long long*)lens)[b] : p32[b]; }

  const float* emc = g_em + (size_t)b * SDIM * TDIM + c;

  float fvown = emc[0];  // t = 0 (lanes c and c+32 load the same)
  fvL[lane] = fvown;

  // 12-deep register prefetch of em (t = 1..12)
  float ebuf[12];
#pragma unroll
  for (int j = 0; j < 12; ++j) ebuf[j] = emc[(size_t)(1 + j) * TDIM];

  unsigned int bpk = 0u;

  // one step: h-split candidates; value via max3 tree + permlane merge;
  // index via eq+min3 + permlane merge (off critical path); branchless freeze
#define VSTEP(T, PH, EV)                                                       \
  {                                                                            \
    float4 q0 = *(const float4*)&fvL[p0];                                      \
    float4 q1 = *(const float4*)&fvL[p0 + 4];                                  \
    float4 q2 = *(const float4*)&fvL[p0 + 8];                                  \
    float4 q3 = *(const float4*)&fvL[p0 + 12];                                 \
    float sv[16];                                                              \
    sv[0] = q0.x + tr[0];  sv[1] = q0.y + tr[1];                               \
    sv[2] = q0.z + tr[2];  sv[3] = q0.w + tr[3];                               \
    sv[4] = q1.x + tr[4];  sv[5] = q1.y + tr[5];                               \
    sv[6] = q1.z + tr[6];  sv[7] = q1.w + tr[7];                               \
    sv[8] = q2.x + tr[8];  sv[9] = q2.y + tr[9];                               \
    sv[10] = q2.z + tr[10]; sv[11] = q2.w + tr[11];                            \
    sv[12] = q3.x + tr[12]; sv[13] = q3.y + tr[13];                            \
    sv[14] = q3.z + tr[14]; sv[15] = q3.w + tr[15];                            \
    float l0 = fmax3(sv[0], sv[1], sv[2]);                                     \
    float l1 = fmax3(sv[3], sv[4], sv[5]);                                     \
    float l2 = fmax3(sv[6], sv[7], sv[8]);                                     \
    float l3 = fmax3(sv[9], sv[10], sv[11]);                                   \
    float l4 = fmax3(sv[12], sv[13], sv[14]);                                  \
    float mh = fmaxf(fmax3(l0, l1, l2), fmax3(l3, l4, sv[15]));                \
    float mo = xor32_f(mh, h);                                                 \
    float m0 = fmaxf(mh, mo);                                                  \
    const bool act = (T) < len;                                                \
    fvown = act ? (m0 + (EV)) : fvown;                                         \
    fvL[lane] = fvown;  /* early write; index path below covers latency */     \
    int i_[16];                                                                \
    _Pragma("unroll")                                                          \
    for (int j = 0; j < 16; ++j) i_[j] = (sv[j] == m0) ? j : 63;               \
    int u0 = imin3(i_[0], i_[1], i_[2]);                                       \
    int u1 = imin3(i_[3], i_[4], i_[5]);                                       \
    int u2 = imin3(i_[6], i_[7], i_[8]);                                       \
    int u3 = imin3(i_[9], i_[10], i_[11]);                                     \
    int u4 = imin3(i_[12], i_[13], i_[14]);                                    \
    int jm = imin3(imin3(u0, u1, u2), imin3(u3, u4, i_[15]), 63);              \
    int gi = (jm == 63) ? 255 : (p0 + jm);                                     \
    int go = xor32_i(gi, h);                                                   \
    int im = gi < go ? gi : go;                                                \
    int bp = act ? im : c;                                                     \
    bpk |= (unsigned)bp << (8 * (PH));                                         \
    if ((PH) == 3) { bps32[(T) >> 2][c] = bpk; bpk = 0u; }                     \
  }

#define LOADQ(BASE, T0)                                                        \
  {                                                                            \
    _Pragma("unroll")                                                          \
    for (int j = 0; j < 4; ++j) {                                              \
      int lt = (T0) + j; lt = lt > (SDIM - 1) ? (SDIM - 1) : lt;               \
      ebuf[(BASE) + j] = emc[(size_t)lt * TDIM];                               \
    }                                                                          \
  }

  {
    int tq = 1;
    for (; tq <= SDIM - 19; tq += 12) {  // t = 1..504
      VSTEP(tq + 0, 1, ebuf[0]) VSTEP(tq + 1, 2, ebuf[1])
      VSTEP(tq + 2, 3, ebuf[2]) VSTEP(tq + 3, 0, ebuf[3])
      LOADQ(0, tq + 12)
      VSTEP(tq + 4, 1, ebuf[4]) VSTEP(tq + 5, 2, ebuf[5])
      VSTEP(tq + 6, 3, ebuf[6]) VSTEP(tq + 7, 0, ebuf[7])
      LOADQ(4, tq + 16)
      VSTEP(tq + 8, 1, ebuf[8]) VSTEP(tq + 9, 2, ebuf[9])
      VSTEP(tq + 10, 3, ebuf[10]) VSTEP(tq + 11, 0, ebuf[11])
      LOADQ(8, tq + 20)
    }
    // tail: t = 505..511
    VSTEP(505, 1, ebuf[0]) VSTEP(506, 2, ebuf[1]) VSTEP(507, 3, ebuf[2])
    VSTEP(508, 0, ebuf[3]) VSTEP(509, 1, ebuf[4]) VSTEP(510, 2, ebuf[5])
    VSTEP(511, 3, ebuf[6])
  }
#undef VSTEP
#undef LOADQ

  // final argmax over tags (lowest index wins); fvown identical across halves
  float bs = fvown;
  int bi = c;
#pragma unroll
  for (int off = 16; off > 0; off >>= 1) {
    float os = __shfl_down(bs, off, 32);
    int oi = __shfl_down(bi, off, 32);
    if (os > bs || (os == bs && oi < bi)) { bs = os; bi = oi; }
  }
  bs = __shfl(bs, 0, 32);
  int tag = __shfl(bi, 0, 32);  // uniform

  out[(size_t)SDIM * BDIM + b] = bs;
  out[(size_t)(SDIM - 1) * BDIM + b] = (float)tag;

  // scalar backtrack via readlane over packed bps words
  unsigned bw_next = bps32[SDIM / 4 - 1][c];
  for (int w = SDIM / 4 - 1; w >= 0; --w) {
    unsigned bw = bw_next;
    if (w > 0) bw_next = bps32[w - 1][c];
#pragma unroll
    for (int j = 3; j >= 0; --j) {
      int t = 4 * w + j;
      if (t < 1) continue;
      unsigned word = (unsigned)__builtin_amdgcn_readlane((int)bw, tag);
      tag = (int)((word >> (8 * j)) & 255u);
      out[(size_t)(t - 1) * BDIM + b] = (float)tag;
    }
  }
}

// ---------------- host ----------------
static int find_by_size(const int* in_sizes, int n_in, int sz, int fb) {
  for (int i = 0; i < n_in; ++i) if (in_sizes[i] == sz) return i;
  return fb;
}

extern "C" void kernel_launch(void* const* d_in, const int* in_sizes, int n_in,
                              void* d_out, int out_size, void* d_ws, size_t ws_size,
                              hipStream_t stream) {
  const int i_hidden = find_by_size(in_sizes, n_in, SDIM * BDIM * HDIM, 0);
  const int i_lens   = find_by_size(in_sizes, n_in, BDIM, 1);
  const int i_W1     = find_by_size(in_sizes, n_in, HDIM * HDIM, 3);
  const int i_b1     = find_by_size(in_sizes, n_in, HDIM, 4);
  const int i_W2     = find_by_size(in_sizes, n_in, HDIM * TDIM, 5);
  const int i_b2     = find_by_size(in_sizes, n_in, TDIM, 6);
  const int i_tr     = find_by_size(in_sizes, n_in, TDIM * TDIM, 7);

  const float* hidden = (const float*)d_in[i_hidden];
  const int*   lens   = (const int*)d_in[i_lens];
  const float* W1     = (const float*)d_in[i_W1];
  const float* b1     = (const float*)d_in[i_b1];
  const float* W2     = (const float*)d_in[i_W2];
  const float* b2     = (const float*)d_in[i_b2];
  const float* trans  = (const float*)d_in[i_tr];
  float* out = (float*)d_out;

  split_kernel<<<HDIM + TDIM, 128, 0, stream>>>(W1, W2);
  emis_kernel<<<SDIM, 256, 0, stream>>>(hidden, b1, b2);
  viterbi_kernel<<<BDIM, 64, 0, stream>>>(lens, trans, out);
}